// Round 17
// baseline (311.177 us; speedup 1.0000x reference)
//
#include <hip/hip_runtime.h>
#include <hip/hip_bf16.h>
#include <math.h>

#define DEV __device__ __forceinline__

static constexpr int HW  = 4096;    // H*W
static constexpr int POS = 8192;    // B*H*W
static constexpr int SLAB = 6 * 64 * 4096;  // one ki-slab (floats)

typedef __attribute__((ext_vector_type(8)))  short short8;
typedef __attribute__((ext_vector_type(16))) float floatx16;

// ---------- B-spline basis (order 3); constant denominators -> mul by recip ----------
template<int G>
DEV void bsplines(float x, float* out /* G+3 values */) {
  const float h = 2.0f / (float)G;
  float knot[G + 7];
#pragma unroll
  for (int t = 0; t < G + 7; ++t) knot[t] = -1.0f + (float)(t - 3) * h;
  float bb[G + 6];
#pragma unroll
  for (int t = 0; t < G + 6; ++t) bb[t] = (x >= knot[t] && x < knot[t + 1]) ? 1.0f : 0.0f;
#pragma unroll
  for (int j = 1; j <= 3; ++j) {
    const float inv = (float)G / (2.0f * (float)j);   // 1/(j*h), compile-time
#pragma unroll
    for (int t = 0; t < G + 6 - j; ++t) {
      float left  = (x - knot[t]) * inv;
      float right = (knot[t + j + 1] - x) * inv;
      bb[t] = left * bb[t] + right * bb[t + 1];
    }
  }
#pragma unroll
  for (int t = 0; t < G + 3; ++t) out[t] = bb[t];
}

DEV float sigmoidf_(float x) { return 1.0f / (1.0f + __expf(-x)); }

DEV float block_reduce_256(float v, float* sb) {  // blockDim.x == 256
  __syncthreads();
#pragma unroll
  for (int off = 32; off > 0; off >>= 1) v += __shfl_down(v, off, 64);
  int lane = threadIdx.x & 63, wid = threadIdx.x >> 6;
  if (lane == 0) sb[wid] = v;
  __syncthreads();
  return sb[0] + sb[1] + sb[2] + sb[3];
}

// ================= prep bodies =================

template<int CF>
DEV void wprep_body(const float* __restrict__ base_w, const float* __restrict__ spline_w,
                    __hip_bfloat16* __restrict__ Wt, int bid) {
  constexpr int KC = 64 * CF;
  int lin = bid * 256 + threadIdx.x;  // (tap, o, ic), 9*64*KC exact
  int ic = lin % KC;
  int rest = lin / KC;
  int o = rest & 63, tap = rest >> 6;
  int c = ic % CF, i = ic / CF;
  float v = (c == 0) ? base_w[(o * 64 + i) * 9 + tap]
                     : spline_w[((o * 64 + i) * 9 + tap) * (CF - 1) + (c - 1)];
  Wt[lin] = __float2bfloat16(v);
}

template<int G>
DEV void c0r_body(int ki, const float* __restrict__ sw, float* __restrict__ out,
                  float* shmem /* >=256 floats */) {
  constexpr int NB = G + 3;
  int o = threadIdx.x & 63, part = threadIdx.x >> 6;  // 4 parts over i
  float b0[NB];
  bsplines<G>(0.0f, b0);
  float s = 0.0f;
  for (int kj = 0; kj < 3; ++kj) {
    int tap = ki * 3 + kj;
    for (int i = part * 16; i < part * 16 + 16; ++i) {
      const float* p = sw + ((size_t)(o * 64 + i) * 9 + tap) * NB;
#pragma unroll
      for (int c = 0; c < NB; ++c) s += p[c] * b0[c];
    }
  }
  shmem[part * 64 + o] = s;
  __syncthreads();
  if (part == 0)
    out[ki * 64 + o] = shmem[o] + shmem[64 + o] + shmem[128 + o] + shmem[192 + o];
}

// ========== features body: F[b][h][wp][ic], LDS-staged coalesced writes ==========
template<int G, int D>
DEV void features_body(const float* __restrict__ x, __hip_bfloat16* __restrict__ F, int bid,
                       __hip_bfloat16* lds /* 4*64*CF bf16 */) {
  constexpr int CF = G + 4;
  constexpr int NB = G + 3;
  constexpr int WP = 64 + 2 * D;
  constexpr int NG = WP / 4;          // 19 | 22 | 25, exact
  constexpr int KC = 64 * CF;
  int i = threadIdx.x & 63, ws = threadIdx.x >> 6;
  int wpg = bid % NG;
  int rest = bid / NG;
  int h = rest & 63, b = rest >> 6;
  int wp = wpg * 4 + ws;
  int w = wp - D;
  float xv = (w >= 0 && w < 64) ? x[((size_t)(b * 64 + i) * 64 + h) * 64 + w] : 0.0f;
  float s = xv * sigmoidf_(xv);
  float bas[NB];
  bsplines<G>(xv, bas);
  __hip_bfloat16* dst = lds + (ws * 64 + i) * CF;
  dst[0] = __float2bfloat16(s);
#pragma unroll
  for (int c = 1; c < CF; ++c) dst[c] = __float2bfloat16(bas[c - 1]);
  __syncthreads();
  constexpr int TOT2 = 4 * 64 * CF / 2;     // uint count
  uint* g = (uint*)(F + ((size_t)((b * 64 + h) * WP) + wpg * 4) * KC);
  const uint* l = (const uint*)lds;
  for (int t = threadIdx.x; t < TOT2; t += 256) g[t] = l[t];
}

// ========== merged prep + features (data-independent, disjoint bid ranges) ==========
__global__ void prepfeat_k(const float* __restrict__ x,
                           __hip_bfloat16* F0, __hip_bfloat16* F1, __hip_bfloat16* F2,
                           const float* bw0, const float* sw0, const float* bw1,
                           const float* sw1, const float* bw2, const float* sw2,
                           __hip_bfloat16* W0, __hip_bfloat16* W1, __hip_bfloat16* W2,
                           float* C0r, const float* fuse_w, float* fwT,
                           float* xm, float* accz /* 896 floats */) {
  __shared__ __hip_bfloat16 lds[4 * 64 * 13];   // features staging (max CF=13)
  __shared__ float shmem[256];                  // prep reductions
  int bid = blockIdx.x, tid = threadIdx.x;
  if (bid < 2432)      { features_body<3, 6>(x, F0, bid, lds); return; }
  else if (bid < 5248) { features_body<6, 12>(x, F1, bid - 2432, lds); return; }
  else if (bid < 8448) { features_body<9, 18>(x, F2, bid - 5248, lds); return; }
  int pb = bid - 8448;                          // [0, 4506) prep blocks
  if (pb < 1008)      { wprep_body<7>(bw0, sw0, W0, pb); }
  else if (pb < 2448) { wprep_body<10>(bw1, sw1, W1, pb - 1008); }
  else if (pb < 4320) { wprep_body<13>(bw2, sw2, W2, pb - 2448); }
  else if (pb < 4329) {
    int idx = pb - 4320, br = idx / 3, ki = idx % 3;
    if (br == 0)      c0r_body<3>(ki, sw0, C0r, shmem);
    else if (br == 1) c0r_body<6>(ki, sw1, C0r + 192, shmem);
    else              c0r_body<9>(ki, sw2, C0r + 384, shmem);
  } else if (pb < 4377) {  // fuse_w transpose (branch part)
    int lin = (pb - 4329) * 256 + tid;  // [0, 12288)
    int o = lin & 63, i2 = lin >> 6;
    fwT[i2 * 64 + o] = fuse_w[o * 256 + i2];
  } else if (pb < 4505) {  // x mean per (b,i)
    int bi = pb - 4377;
    const float* p = x + (size_t)bi * HW;
    float s = 0.0f;
    for (int t = tid; t < HW; t += 256) s += p[t];
    s = block_reduce_256(s, shmem);
    if (tid == 0) xm[bi] = s * (1.0f / HW);
  } else {  // zero accumulators: fstat[128] | bnacc_s[192] | bnacc_q[192] | se_acc[384]
    for (int t = tid; t < 896; t += 256) accz[t] = 0.0f;
  }
}

// ============ KAN conv: R4's proven structure (90.8 us) — byte-identical ============
DEV floatx16 mfma_bf16(short8 a, short8 b, floatx16 c) {
  return __builtin_amdgcn_mfma_f32_32x32x16_bf16(a, b, c, 0, 0, 0);
}

template<int CF, int DD>
DEV void conv_dev(int ki, int b, int hp, const short* __restrict__ F,
                  const short* __restrict__ W, const float* __restrict__ C0r,
                  float* __restrict__ ypart, int br) {
  constexpr int KC = 64 * CF;
  constexpr int WP = 64 + 2 * DD;
  int wv = threadIdx.x >> 6;
  int lane = threadIdx.x & 63;
  int lr = lane & 31, lq = lane >> 5;
  int hs = hp * 2 + wv;             // source row (always valid)
  int h_out = hs - (ki - 1) * DD;   // output row this source feeds for this ki
  bool valid = (h_out >= 0 && h_out < 64);
  int h_tgt = valid ? h_out : (h_out < 0 ? h_out + 64 : h_out - 64);  // mirror: C0 rows
  float* yb = ypart + (size_t)ki * SLAB + ((size_t)((br * 2 + b) * 64 + h_tgt)) * 4096;

  if (!valid) {  // paired output row's source is OOB: constant C0 contribution
    const float* c0 = C0r + (br * 3 + ki) * 64;
#pragma unroll
    for (int wh = 0; wh < 2; ++wh) {
      int w = wh * 32 + lr;
#pragma unroll
      for (int ot = 0; ot < 2; ++ot)
#pragma unroll
        for (int reg = 0; reg < 16; ++reg) {
          int o = (reg & 3) + 8 * (reg >> 2) + 4 * lq + 32 * ot;
          yb[(size_t)o * 64 + w] = c0[o];
        }
    }
    return;
  }

  floatx16 acc[2][2];
#pragma unroll
  for (int ot = 0; ot < 2; ++ot)
#pragma unroll
    for (int wh = 0; wh < 2; ++wh)
#pragma unroll
      for (int r = 0; r < 16; ++r) acc[ot][wh][r] = 0.0f;

  const short* rowF = F + (size_t)(b * 64 + hs) * WP * KC;
  const short* wb = W + (size_t)(ki * 3) * 64 * KC + lr * KC + lq * 8;
  const short* fb = rowF + lr * KC + lq * 8;
#pragma unroll
  for (int kj = 0; kj < 3; ++kj) {
    const short* w0p = wb + kj * (64 * KC);
    const short* f0p = fb + kj * (DD * KC);
#pragma unroll 4
    for (int s = 0; s < 4 * CF; ++s) {   // 16-K per step, all offsets affine
      short8 a0 = *(const short8*)(w0p + s * 16);
      short8 a1 = *(const short8*)(w0p + 32 * KC + s * 16);
      short8 b0 = *(const short8*)(f0p + s * 16);
      short8 b1 = *(const short8*)(f0p + 32 * KC + s * 16);
      acc[0][0] = mfma_bf16(a0, b0, acc[0][0]);
      acc[0][1] = mfma_bf16(a0, b1, acc[0][1]);
      acc[1][0] = mfma_bf16(a1, b0, acc[1][0]);
      acc[1][1] = mfma_bf16(a1, b1, acc[1][1]);
    }
  }

#pragma unroll
  for (int ot = 0; ot < 2; ++ot)
#pragma unroll
    for (int wh = 0; wh < 2; ++wh) {
      int w = wh * 32 + lr;
#pragma unroll
      for (int reg = 0; reg < 16; ++reg) {
        int o = (reg & 3) + 8 * (reg >> 2) + 4 * lq + 32 * ot;
        yb[(size_t)o * 64 + w] = acc[ot][wh][reg];
      }
    }
}

__global__ __launch_bounds__(128) void conv_all_k(
    const short* __restrict__ F0, const short* __restrict__ F1, const short* __restrict__ F2,
    const short* __restrict__ W0, const short* __restrict__ W1, const short* __restrict__ W2,
    const float* __restrict__ C0r, float* __restrict__ ypart) {
  // XCD swizzle: ki-siblings at bid, bid+8, bid+16 -> same XCD (bid % 8 fixed)
  int bid = blockIdx.x;                 // [0,576)
  int e  = bid & 7;
  int t  = bid >> 3;                    // [0,72)
  int ki = t % 3;
  int m  = (t / 3) * 8 + e;             // [0,192) combo (br,b,hp)
  int br = m >> 6, b = (m >> 5) & 1, hp = m & 31;
  if (br == 0)      conv_dev<7, 6>(ki, b, hp, F0, W0, C0r, ypart, 0);
  else if (br == 1) conv_dev<10, 12>(ki, b, hp, F1, W1, C0r, ypart, 1);
  else              conv_dev<13, 18>(ki, b, hp, F2, W2, C0r, ypart, 2);
}

// ====== reduce 3 ki-slabs into slab0 + atomic per-(br,o) BN partials ======
__global__ void rb_k(float* __restrict__ yp, float* __restrict__ bnacc_s,
                     float* __restrict__ bnacc_q) {
  int bid = blockIdx.x;                 // [0,1536) = bb(6) x chunk(256)
  int bb = bid / 256, chunk = bid % 256;
  int br = bb >> 1;
  int tid = threadIdx.x;
  size_t base = (size_t)bb * 262144 + chunk * 1024 + tid * 4;
  float4 v = *(const float4*)(yp + base);
#pragma unroll
  for (int s2 = 1; s2 < 3; ++s2) {
    float4 u = *(const float4*)(yp + base + (size_t)s2 * SLAB);
    v.x += u.x; v.y += u.y; v.z += u.z; v.w += u.w;
  }
  *(float4*)(yp + base) = v;
  float s = v.x + v.y + v.z + v.w;
  float q = v.x * v.x + v.y * v.y + v.z * v.z + v.w * v.w;
  s += __shfl_down(s, 8, 16); s += __shfl_down(s, 4, 16);
  s += __shfl_down(s, 2, 16); s += __shfl_down(s, 1, 16);
  q += __shfl_down(q, 8, 16); q += __shfl_down(q, 4, 16);
  q += __shfl_down(q, 2, 16); q += __shfl_down(q, 1, 16);
  if ((tid & 15) == 0) {
    int o = (chunk * 16 + (tid >> 4)) & 63;
    atomicAdd(&bnacc_s[br * 64 + o], s);
    atomicAdd(&bnacc_q[br * 64 + o], q);
  }
}

// ====== SE pre-sum: atomic sum over (h,w) of relu(bn(y)) per (bb,o) ======
__global__ void sesum_k(const float* __restrict__ y, const float* __restrict__ bnacc_s,
                        const float* __restrict__ bnacc_q,
                        const float* g0, const float* b0p, const float* g1, const float* b1p,
                        const float* g2, const float* b2p, float* __restrict__ se_acc) {
  int bid = blockIdx.x;                 // [0,384) = bb(6) x h(64)
  int bb = bid >> 6, h = bid & 63;
  int br = bb >> 1;
  int tid = threadIdx.x;
  int o = tid >> 2, wq = tid & 3;
  const float* gptr = (br == 0) ? g0 : ((br == 1) ? g1 : g2);
  const float* bptr = (br == 0) ? b0p : ((br == 1) ? b1p : b2p);
  float mu = bnacc_s[br * 64 + o] * (1.0f / POS);
  float var = bnacc_q[br * 64 + o] * (1.0f / POS) - mu * mu;
  float kk = gptr[o] / sqrtf(var + 1e-5f);
  float cc = bptr[o] - mu * kk;
  const float* row = y + (size_t)bb * 262144 + (size_t)h * 4096 + o * 64 + wq * 16;
  float s = 0.0f;
#pragma unroll
  for (int j = 0; j < 4; ++j) {
    float4 v = *(const float4*)(row + j * 4);
    float a;
    a = v.x * kk + cc; s += (a > 0.0f) ? a : 0.0f;
    a = v.y * kk + cc; s += (a > 0.0f) ? a : 0.0f;
    a = v.z * kk + cc; s += (a > 0.0f) ? a : 0.0f;
    a = v.w * kk + cc; s += (a > 0.0f) ? a : 0.0f;
  }
  s += __shfl_down(s, 2, 4);
  s += __shfl_down(s, 1, 4);
  if (wq == 0) atomicAdd(&se_acc[bb * 64 + o], s);
}

// ==== fuse GEMM + inlined SE-MLP/gp fold (R13-proven) + fstat atomics ====
__global__ __launch_bounds__(256) void fuse_k(
    const float* __restrict__ y, const float* __restrict__ se_acc,
    const float* __restrict__ bnacc_s, const float* __restrict__ bnacc_q,
    const float* g0, const float* b0p, const float* g1, const float* b1p,
    const float* g2, const float* b2p,
    const float* w10, const float* w11, const float* w12,
    const float* w20, const float* w21, const float* w22,
    const float* __restrict__ xm, const float* __restrict__ gw,
    const float* __restrict__ gb, const float* __restrict__ bng,
    const float* __restrict__ bnb, const float* __restrict__ gpw1,
    const float* __restrict__ gpw2, const float* __restrict__ fuse_w,
    const float* __restrict__ fwT, const float* __restrict__ fb,
    float* __restrict__ tmp, float* __restrict__ fstat) {
  __shared__ float As[64][32];
  __shared__ float Ws[64][64];
  __shared__ float sem[384], A1l[384], A0l[384], fgpl[128], gsc[384];
  int bid = blockIdx.x;           // [0,256): (b, h, w-half)
  int b = bid >> 7, h = (bid >> 1) & 63, wh = bid & 1;
  int tid = threadIdx.x;

  // stage SE means (raw atomic sums scaled by 1/HW)
  for (int u = tid; u < 384; u += 256) sem[u] = se_acc[u] * (1.0f / HW);
  __syncthreads();
  // gp linear step + A1/A0 fold
  if (tid < 128) {
    int bgp = tid >> 6, o = tid & 63;
    float gv = gb[o];
    for (int i = 0; i < 64; ++i) gv += xm[bgp * 64 + i] * gw[o * 64 + i];
    gsc[tid] = gv;
  }
  if (tid < 64) {
    int o = tid;
#pragma unroll
    for (int bb = 0; bb < 6; ++bb) {
      int br = bb >> 1;
      const float* w1 = (br == 0) ? w10 : ((br == 1) ? w11 : w12);
      const float* w2 = (br == 0) ? w20 : ((br == 1) ? w21 : w22);
      const float* g_ = (br == 0) ? g0 : ((br == 1) ? g1 : g2);
      const float* b_ = (br == 0) ? b0p : ((br == 1) ? b1p : b2p);
      float z[4];
#pragma unroll
      for (int j = 0; j < 4; ++j) {
        float s = 0.0f;
        for (int c2 = 0; c2 < 64; ++c2) s += sem[bb * 64 + c2] * w1[j * 64 + c2];
        z[j] = (s > 0.0f) ? s : 0.0f;
      }
      float t = 0.0f;
#pragma unroll
      for (int j = 0; j < 4; ++j) t += z[j] * w2[o * 4 + j];
      t = sigmoidf_(t);
      float mu = bnacc_s[br * 64 + o] * (1.0f / POS);
      float var = bnacc_q[br * 64 + o] * (1.0f / POS) - mu * mu;
      float kk = g_[o] / sqrtf(var + 1e-5f);
      float cc = b_[o] - mu * kk;
      A1l[bb * 64 + o] = kk * t;    // relu(x)*t == relu(x*t), t>0
      A0l[bb * 64 + o] = cc * t;
    }
  }
  __syncthreads();
  if (tid < 128) {                // gp bn+relu (exact population var for N=2)
    int o = tid & 63;
    float mu = 0.5f * (gsc[o] + gsc[64 + o]);
    float df = gsc[o] - gsc[64 + o];
    float var = 0.25f * df * df;
    float v = (gsc[tid] - mu) / sqrtf(var + 1e-5f) * bng[o] + bnb[o];
    gsc[128 + tid] = (v > 0.0f) ? v : 0.0f;
  }
  __syncthreads();
  if (tid < 128) {                // gp SE MLP
    int bgp = tid >> 6, o = tid & 63;
    float z[4];
#pragma unroll
    for (int j = 0; j < 4; ++j) {
      float s = 0.0f;
      for (int c2 = 0; c2 < 64; ++c2) s += gsc[128 + bgp * 64 + c2] * gpw1[j * 64 + c2];
      z[j] = (s > 0.0f) ? s : 0.0f;
    }
    float t = 0.0f;
#pragma unroll
    for (int j = 0; j < 4; ++j) t += z[j] * gpw2[o * 4 + j];
    t = sigmoidf_(t);
    gsc[256 + tid] = gsc[128 + tid] * t;
  }
  __syncthreads();
  if (tid < 128) {                // fold gp into per-(b,o) fuse bias
    int bgp = tid >> 6, o = tid & 63;
    float fg = 0.0f;
    for (int c2 = 0; c2 < 64; ++c2) fg += fuse_w[o * 256 + 192 + c2] * gsc[256 + bgp * 64 + c2];
    fgpl[tid] = fg;
  }
  __syncthreads();

  // fuse GEMM over 3 branches (A1/A0 from LDS)
  int wg = tid & 7, og = tid >> 3;      // 8 w-groups x 32 o-groups
  int w0 = wg * 4, o0 = og * 2;
  float acc[2][4] = {};
  for (int br = 0; br < 3; ++br) {
#pragma unroll
    for (int m = 0; m < 8; ++m) {       // stage As: 64 oc x 32 w
      int lin = tid + m * 256;
      int oc = lin >> 5, wl = lin & 31;
      float v = y[(size_t)(br * 2 + b) * 262144 + (size_t)h * 4096 + oc * 64 + wh * 32 + wl];
      int idx = (br * 2 + b) * 64 + oc;
      v = v * A1l[idx] + A0l[idx];
      As[oc][wl] = (v > 0.0f) ? v : 0.0f;
    }
#pragma unroll
    for (int m = 0; m < 16; ++m) {      // stage Ws: 64 oc x 64 o
      int lin = tid + m * 256;
      int oc = lin >> 6, ol = lin & 63;
      Ws[oc][ol] = fwT[(br * 64 + oc) * 64 + ol];
    }
    __syncthreads();
#pragma unroll 8
    for (int ict = 0; ict < 64; ++ict) {
      float4 a = *reinterpret_cast<const float4*>(&As[ict][w0]);
      float2 wv = *reinterpret_cast<const float2*>(&Ws[ict][o0]);
      acc[0][0] += wv.x * a.x; acc[0][1] += wv.x * a.y; acc[0][2] += wv.x * a.z; acc[0][3] += wv.x * a.w;
      acc[1][0] += wv.y * a.x; acc[1][1] += wv.y * a.y; acc[1][2] += wv.y * a.z; acc[1][3] += wv.y * a.w;
    }
    __syncthreads();
  }
  float* tp = tmp + (size_t)(b * 64 + h) * 4096 + wh * 32;
  float ps[2], pq[2];
#pragma unroll
  for (int oo = 0; oo < 2; ++oo) {
    int o = o0 + oo;
    float bias = fb[o] + fgpl[b * 64 + o];
    float4 v = make_float4(acc[oo][0] + bias, acc[oo][1] + bias,
                           acc[oo][2] + bias, acc[oo][3] + bias);
    *reinterpret_cast<float4*>(&tp[o * 64 + w0]) = v;
    ps[oo] = v.x + v.y + v.z + v.w;
    pq[oo] = v.x * v.x + v.y * v.y + v.z * v.z + v.w * v.w;
  }
  __syncthreads();
#pragma unroll
  for (int oo = 0; oo < 2; ++oo) { As[o0 + oo][wg] = ps[oo]; Ws[o0 + oo][wg] = pq[oo]; }
  __syncthreads();
  if (tid < 64) {
    float s = 0.0f, q = 0.0f;
#pragma unroll
    for (int r = 0; r < 8; ++r) { s += As[tid][r]; q += Ws[tid][r]; }
    atomicAdd(&fstat[tid], s);
    atomicAdd(&fstat[64 + tid], q);
  }
}

// ---------- final BN+relu, write (B,Co,H,W) ----------
__global__ void final_k(const float* __restrict__ tmp, const float* __restrict__ fstat,
                        const float* __restrict__ g, const float* __restrict__ bb,
                        float* __restrict__ out) {
  int lin = blockIdx.x * 256 + threadIdx.x;  // [0, 524288)
  int w = lin & 63, h2 = (lin >> 6) & 63, o = (lin >> 12) & 63, b = lin >> 18;
  float v = tmp[((size_t)(b * 64 + h2) * 64 + o) * 64 + w];
  float m = fstat[o] * (1.0f / POS);
  float var = fstat[64 + o] * (1.0f / POS) - m * m;
  float kk = g[o] / sqrtf(var + 1e-5f);
  float r = (v - m) * kk + bb[o];
  out[lin] = (r > 0.0f) ? r : 0.0f;
}

extern "C" void kernel_launch(void* const* d_in, const int* in_sizes, int n_in,
                              void* d_out, int out_size, void* d_ws, size_t ws_size,
                              hipStream_t stream) {
  const float* x = (const float*)d_in[0];
  const float* base_w[3]   = {(const float*)d_in[1],  (const float*)d_in[7],  (const float*)d_in[13]};
  const float* spline_w[3] = {(const float*)d_in[2],  (const float*)d_in[8],  (const float*)d_in[14]};
  const float* bn_g[3]     = {(const float*)d_in[3],  (const float*)d_in[9],  (const float*)d_in[15]};
  const float* bn_b[3]     = {(const float*)d_in[4],  (const float*)d_in[10], (const float*)d_in[16]};
  const float* se_w1[3]    = {(const float*)d_in[5],  (const float*)d_in[11], (const float*)d_in[17]};
  const float* se_w2[3]    = {(const float*)d_in[6],  (const float*)d_in[12], (const float*)d_in[18]};
  const float* gp_conv_w = (const float*)d_in[19];
  const float* gp_conv_b = (const float*)d_in[20];
  const float* gp_bn_g   = (const float*)d_in[21];
  const float* gp_bn_b   = (const float*)d_in[22];
  const float* gp_se_w1  = (const float*)d_in[23];
  const float* gp_se_w2  = (const float*)d_in[24];
  const float* fuse_w    = (const float*)d_in[25];
  const float* fuse_b    = (const float*)d_in[26];
  const float* fuse_bn_g = (const float*)d_in[27];
  const float* fuse_bn_b = (const float*)d_in[28];
  float* out = (float*)d_out;

  char* wsp = (char*)d_ws;
  auto alloc = [&](size_t bytes) -> char* {
    char* p = wsp;
    wsp += (bytes + 255) & ~(size_t)255;
    return p;
  };
  __hip_bfloat16* F0 = (__hip_bfloat16*)alloc((size_t)2 * 64 * 76 * 448 * 2);
  __hip_bfloat16* F1 = (__hip_bfloat16*)alloc((size_t)2 * 64 * 88 * 640 * 2);
  __hip_bfloat16* F2 = (__hip_bfloat16*)alloc((size_t)2 * 64 * 100 * 832 * 2);
  __hip_bfloat16* W0 = (__hip_bfloat16*)alloc((size_t)9 * 64 * 448 * 2);
  __hip_bfloat16* W1 = (__hip_bfloat16*)alloc((size_t)9 * 64 * 640 * 2);
  __hip_bfloat16* W2 = (__hip_bfloat16*)alloc((size_t)9 * 64 * 832 * 2);
  float* C0r   = (float*)alloc((size_t)3 * 3 * 64 * 4);
  float* ypart = (float*)alloc((size_t)3 * SLAB * 4);   // 3 ki-slabs; slab0 -> y
  float* y     = ypart;
  float* tmp   = ypart + SLAB;   // slab1 dead after rb_k -> reuse
  float* xm  = (float*)alloc(128 * 4);
  float* fwT = (float*)alloc((size_t)12288 * 4);
  float* accz = (float*)alloc(896 * 4);  // fstat[128] | bnacc_s[192] | bnacc_q[192] | se_acc[384]
  float* fstat   = accz;
  float* bnacc_s = accz + 128;
  float* bnacc_q = accz + 320;
  float* se_acc  = accz + 512;

  prepfeat_k<<<12954, 256, 0, stream>>>(x, F0, F1, F2,
                                        base_w[0], spline_w[0], base_w[1], spline_w[1],
                                        base_w[2], spline_w[2], W0, W1, W2, C0r,
                                        fuse_w, fwT, xm, accz);
  conv_all_k<<<576, 128, 0, stream>>>(
      (const short*)F0, (const short*)F1, (const short*)F2,
      (const short*)W0, (const short*)W1, (const short*)W2, C0r, ypart);
  rb_k<<<1536, 256, 0, stream>>>(ypart, bnacc_s, bnacc_q);
  sesum_k<<<384, 256, 0, stream>>>(y, bnacc_s, bnacc_q, bn_g[0], bn_b[0], bn_g[1], bn_b[1],
                                   bn_g[2], bn_b[2], se_acc);
  fuse_k<<<256, 256, 0, stream>>>(y, se_acc, bnacc_s, bnacc_q,
                                  bn_g[0], bn_b[0], bn_g[1], bn_b[1], bn_g[2], bn_b[2],
                                  se_w1[0], se_w1[1], se_w1[2], se_w2[0], se_w2[1], se_w2[2],
                                  xm, gp_conv_w, gp_conv_b, gp_bn_g, gp_bn_b,
                                  gp_se_w1, gp_se_w2, fuse_w, fwT, fuse_b, tmp, fstat);
  final_k<<<2048, 256, 0, stream>>>(tmp, fstat, fuse_bn_g, fuse_bn_b, out);
}

// Round 18
// 287.302 us; speedup vs baseline: 1.0831x; 1.0831x over previous
//
#include <hip/hip_runtime.h>
#include <hip/hip_bf16.h>
#include <math.h>

#define DEV __device__ __forceinline__

static constexpr int HW  = 4096;    // H*W
static constexpr int POS = 8192;    // B*H*W
static constexpr int SLAB = 6 * 64 * 4096;  // one ki-slab (floats)

typedef __attribute__((ext_vector_type(8)))  short short8;
typedef __attribute__((ext_vector_type(16))) float floatx16;

// ---------- B-spline basis (order 3); constant denominators -> mul by recip ----------
template<int G>
DEV void bsplines(float x, float* out /* G+3 values */) {
  const float h = 2.0f / (float)G;
  float knot[G + 7];
#pragma unroll
  for (int t = 0; t < G + 7; ++t) knot[t] = -1.0f + (float)(t - 3) * h;
  float bb[G + 6];
#pragma unroll
  for (int t = 0; t < G + 6; ++t) bb[t] = (x >= knot[t] && x < knot[t + 1]) ? 1.0f : 0.0f;
#pragma unroll
  for (int j = 1; j <= 3; ++j) {
    const float inv = (float)G / (2.0f * (float)j);   // 1/(j*h), compile-time
#pragma unroll
    for (int t = 0; t < G + 6 - j; ++t) {
      float left  = (x - knot[t]) * inv;
      float right = (knot[t + j + 1] - x) * inv;
      bb[t] = left * bb[t] + right * bb[t + 1];
    }
  }
#pragma unroll
  for (int t = 0; t < G + 3; ++t) out[t] = bb[t];
}

DEV float sigmoidf_(float x) { return 1.0f / (1.0f + __expf(-x)); }

DEV float block_reduce_256(float v, float* sb) {  // blockDim.x == 256
  __syncthreads();
#pragma unroll
  for (int off = 32; off > 0; off >>= 1) v += __shfl_down(v, off, 64);
  int lane = threadIdx.x & 63, wid = threadIdx.x >> 6;
  if (lane == 0) sb[wid] = v;
  __syncthreads();
  return sb[0] + sb[1] + sb[2] + sb[3];
}

// ================= prep bodies =================

template<int CF>
DEV void wprep_body(const float* __restrict__ base_w, const float* __restrict__ spline_w,
                    __hip_bfloat16* __restrict__ Wt, int bid) {
  constexpr int KC = 64 * CF;
  int lin = bid * 256 + threadIdx.x;  // (tap, o, ic), 9*64*KC exact
  int ic = lin % KC;
  int rest = lin / KC;
  int o = rest & 63, tap = rest >> 6;
  int c = ic % CF, i = ic / CF;
  float v = (c == 0) ? base_w[(o * 64 + i) * 9 + tap]
                     : spline_w[((o * 64 + i) * 9 + tap) * (CF - 1) + (c - 1)];
  Wt[lin] = __float2bfloat16(v);
}

template<int G>
DEV void c0r_body(int ki, const float* __restrict__ sw, float* __restrict__ out,
                  float* shmem /* >=256 floats */) {
  constexpr int NB = G + 3;
  int o = threadIdx.x & 63, part = threadIdx.x >> 6;  // 4 parts over i
  float b0[NB];
  bsplines<G>(0.0f, b0);
  float s = 0.0f;
  for (int kj = 0; kj < 3; ++kj) {
    int tap = ki * 3 + kj;
    for (int i = part * 16; i < part * 16 + 16; ++i) {
      const float* p = sw + ((size_t)(o * 64 + i) * 9 + tap) * NB;
#pragma unroll
      for (int c = 0; c < NB; ++c) s += p[c] * b0[c];
    }
  }
  shmem[part * 64 + o] = s;
  __syncthreads();
  if (part == 0)
    out[ki * 64 + o] = shmem[o] + shmem[64 + o] + shmem[128 + o] + shmem[192 + o];
}

// ========== features body: F[b][h][wp][ic], LDS-staged coalesced writes ==========
template<int G, int D>
DEV void features_body(const float* __restrict__ x, __hip_bfloat16* __restrict__ F, int bid,
                       __hip_bfloat16* lds /* 4*64*CF bf16 */) {
  constexpr int CF = G + 4;
  constexpr int NB = G + 3;
  constexpr int WP = 64 + 2 * D;
  constexpr int NG = WP / 4;          // 19 | 22 | 25, exact
  constexpr int KC = 64 * CF;
  int i = threadIdx.x & 63, ws = threadIdx.x >> 6;
  int wpg = bid % NG;
  int rest = bid / NG;
  int h = rest & 63, b = rest >> 6;
  int wp = wpg * 4 + ws;
  int w = wp - D;
  float xv = (w >= 0 && w < 64) ? x[((size_t)(b * 64 + i) * 64 + h) * 64 + w] : 0.0f;
  float s = xv * sigmoidf_(xv);
  float bas[NB];
  bsplines<G>(xv, bas);
  __hip_bfloat16* dst = lds + (ws * 64 + i) * CF;
  dst[0] = __float2bfloat16(s);
#pragma unroll
  for (int c = 1; c < CF; ++c) dst[c] = __float2bfloat16(bas[c - 1]);
  __syncthreads();
  constexpr int TOT2 = 4 * 64 * CF / 2;     // uint count
  uint* g = (uint*)(F + ((size_t)((b * 64 + h) * WP) + wpg * 4) * KC);
  const uint* l = (const uint*)lds;
  for (int t = threadIdx.x; t < TOT2; t += 256) g[t] = l[t];
}

// ========== merged prep + features (data-independent, disjoint bid ranges) ==========
__global__ void prepfeat_k(const float* __restrict__ x,
                           __hip_bfloat16* F0, __hip_bfloat16* F1, __hip_bfloat16* F2,
                           const float* bw0, const float* sw0, const float* bw1,
                           const float* sw1, const float* bw2, const float* sw2,
                           __hip_bfloat16* W0, __hip_bfloat16* W1, __hip_bfloat16* W2,
                           float* C0r, const float* fuse_w, float* fwT,
                           float* xm, float* accz /* 896 floats */) {
  __shared__ __hip_bfloat16 lds[4 * 64 * 13];   // features staging (max CF=13)
  __shared__ float shmem[256];                  // prep reductions
  int bid = blockIdx.x, tid = threadIdx.x;
  if (bid < 2432)      { features_body<3, 6>(x, F0, bid, lds); return; }
  else if (bid < 5248) { features_body<6, 12>(x, F1, bid - 2432, lds); return; }
  else if (bid < 8448) { features_body<9, 18>(x, F2, bid - 5248, lds); return; }
  int pb = bid - 8448;                          // [0, 4506) prep blocks
  if (pb < 1008)      { wprep_body<7>(bw0, sw0, W0, pb); }
  else if (pb < 2448) { wprep_body<10>(bw1, sw1, W1, pb - 1008); }
  else if (pb < 4320) { wprep_body<13>(bw2, sw2, W2, pb - 2448); }
  else if (pb < 4329) {
    int idx = pb - 4320, br = idx / 3, ki = idx % 3;
    if (br == 0)      c0r_body<3>(ki, sw0, C0r, shmem);
    else if (br == 1) c0r_body<6>(ki, sw1, C0r + 192, shmem);
    else              c0r_body<9>(ki, sw2, C0r + 384, shmem);
  } else if (pb < 4377) {  // fuse_w transpose (branch part)
    int lin = (pb - 4329) * 256 + tid;  // [0, 12288)
    int o = lin & 63, i2 = lin >> 6;
    fwT[i2 * 64 + o] = fuse_w[o * 256 + i2];
  } else if (pb < 4505) {  // x mean per (b,i)
    int bi = pb - 4377;
    const float* p = x + (size_t)bi * HW;
    float s = 0.0f;
    for (int t = tid; t < HW; t += 256) s += p[t];
    s = block_reduce_256(s, shmem);
    if (tid == 0) xm[bi] = s * (1.0f / HW);
  } else {  // zero accumulators: fstat[128] | bnacc_s[192] | bnacc_q[192] | se_acc[384]
    for (int t = tid; t < 896; t += 256) accz[t] = 0.0f;
  }
}

// ============ KAN conv: R4's proven structure (90.8 us) — byte-identical ============
DEV floatx16 mfma_bf16(short8 a, short8 b, floatx16 c) {
  return __builtin_amdgcn_mfma_f32_32x32x16_bf16(a, b, c, 0, 0, 0);
}

template<int CF, int DD>
DEV void conv_dev(int ki, int b, int hp, const short* __restrict__ F,
                  const short* __restrict__ W, const float* __restrict__ C0r,
                  float* __restrict__ ypart, int br) {
  constexpr int KC = 64 * CF;
  constexpr int WP = 64 + 2 * DD;
  int wv = threadIdx.x >> 6;
  int lane = threadIdx.x & 63;
  int lr = lane & 31, lq = lane >> 5;
  int hs = hp * 2 + wv;             // source row (always valid)
  int h_out = hs - (ki - 1) * DD;   // output row this source feeds for this ki
  bool valid = (h_out >= 0 && h_out < 64);
  int h_tgt = valid ? h_out : (h_out < 0 ? h_out + 64 : h_out - 64);  // mirror: C0 rows
  float* yb = ypart + (size_t)ki * SLAB + ((size_t)((br * 2 + b) * 64 + h_tgt)) * 4096;

  if (!valid) {  // paired output row's source is OOB: constant C0 contribution
    const float* c0 = C0r + (br * 3 + ki) * 64;
#pragma unroll
    for (int wh = 0; wh < 2; ++wh) {
      int w = wh * 32 + lr;
#pragma unroll
      for (int ot = 0; ot < 2; ++ot)
#pragma unroll
        for (int reg = 0; reg < 16; ++reg) {
          int o = (reg & 3) + 8 * (reg >> 2) + 4 * lq + 32 * ot;
          yb[(size_t)o * 64 + w] = c0[o];
        }
    }
    return;
  }

  floatx16 acc[2][2];
#pragma unroll
  for (int ot = 0; ot < 2; ++ot)
#pragma unroll
    for (int wh = 0; wh < 2; ++wh)
#pragma unroll
      for (int r = 0; r < 16; ++r) acc[ot][wh][r] = 0.0f;

  const short* rowF = F + (size_t)(b * 64 + hs) * WP * KC;
  const short* wb = W + (size_t)(ki * 3) * 64 * KC + lr * KC + lq * 8;
  const short* fb = rowF + lr * KC + lq * 8;
#pragma unroll
  for (int kj = 0; kj < 3; ++kj) {
    const short* w0p = wb + kj * (64 * KC);
    const short* f0p = fb + kj * (DD * KC);
#pragma unroll 4
    for (int s = 0; s < 4 * CF; ++s) {   // 16-K per step, all offsets affine
      short8 a0 = *(const short8*)(w0p + s * 16);
      short8 a1 = *(const short8*)(w0p + 32 * KC + s * 16);
      short8 b0 = *(const short8*)(f0p + s * 16);
      short8 b1 = *(const short8*)(f0p + 32 * KC + s * 16);
      acc[0][0] = mfma_bf16(a0, b0, acc[0][0]);
      acc[0][1] = mfma_bf16(a0, b1, acc[0][1]);
      acc[1][0] = mfma_bf16(a1, b0, acc[1][0]);
      acc[1][1] = mfma_bf16(a1, b1, acc[1][1]);
    }
  }

#pragma unroll
  for (int ot = 0; ot < 2; ++ot)
#pragma unroll
    for (int wh = 0; wh < 2; ++wh) {
      int w = wh * 32 + lr;
#pragma unroll
      for (int reg = 0; reg < 16; ++reg) {
        int o = (reg & 3) + 8 * (reg >> 2) + 4 * lq + 32 * ot;
        yb[(size_t)o * 64 + w] = acc[ot][wh][reg];
      }
    }
}

__global__ __launch_bounds__(128) void conv_all_k(
    const short* __restrict__ F0, const short* __restrict__ F1, const short* __restrict__ F2,
    const short* __restrict__ W0, const short* __restrict__ W1, const short* __restrict__ W2,
    const float* __restrict__ C0r, float* __restrict__ ypart) {
  // XCD swizzle: ki-siblings at bid, bid+8, bid+16 -> same XCD (bid % 8 fixed)
  int bid = blockIdx.x;                 // [0,576)
  int e  = bid & 7;
  int t  = bid >> 3;                    // [0,72)
  int ki = t % 3;
  int m  = (t / 3) * 8 + e;             // [0,192) combo (br,b,hp)
  int br = m >> 6, b = (m >> 5) & 1, hp = m & 31;
  if (br == 0)      conv_dev<7, 6>(ki, b, hp, F0, W0, C0r, ypart, 0);
  else if (br == 1) conv_dev<10, 12>(ki, b, hp, F1, W1, C0r, ypart, 1);
  else              conv_dev<13, 18>(ki, b, hp, F2, W2, C0r, ypart, 2);
}

// ====== reduce 3 ki-slabs into slab0 + atomic per-(br,o) BN partials ======
__global__ void rb_k(float* __restrict__ yp, float* __restrict__ bnacc_s,
                     float* __restrict__ bnacc_q) {
  int bid = blockIdx.x;                 // [0,1536) = bb(6) x chunk(256)
  int bb = bid / 256, chunk = bid % 256;
  int br = bb >> 1;
  int tid = threadIdx.x;
  size_t base = (size_t)bb * 262144 + chunk * 1024 + tid * 4;
  float4 v = *(const float4*)(yp + base);
#pragma unroll
  for (int s2 = 1; s2 < 3; ++s2) {
    float4 u = *(const float4*)(yp + base + (size_t)s2 * SLAB);
    v.x += u.x; v.y += u.y; v.z += u.z; v.w += u.w;
  }
  *(float4*)(yp + base) = v;
  float s = v.x + v.y + v.z + v.w;
  float q = v.x * v.x + v.y * v.y + v.z * v.z + v.w * v.w;
  s += __shfl_down(s, 8, 16); s += __shfl_down(s, 4, 16);
  s += __shfl_down(s, 2, 16); s += __shfl_down(s, 1, 16);
  q += __shfl_down(q, 8, 16); q += __shfl_down(q, 4, 16);
  q += __shfl_down(q, 2, 16); q += __shfl_down(q, 1, 16);
  if ((tid & 15) == 0) {
    int o = (chunk * 16 + (tid >> 4)) & 63;
    atomicAdd(&bnacc_s[br * 64 + o], s);
    atomicAdd(&bnacc_q[br * 64 + o], q);
  }
}

// ====== SE pre-sum: atomic sum over (h,w) of relu(bn(y)) per (bb,o) ======
__global__ void sesum_k(const float* __restrict__ y, const float* __restrict__ bnacc_s,
                        const float* __restrict__ bnacc_q,
                        const float* g0, const float* b0p, const float* g1, const float* b1p,
                        const float* g2, const float* b2p, float* __restrict__ se_acc) {
  int bid = blockIdx.x;                 // [0,384) = bb(6) x h(64)
  int bb = bid >> 6, h = bid & 63;
  int br = bb >> 1;
  int tid = threadIdx.x;
  int o = tid >> 2, wq = tid & 3;
  const float* gptr = (br == 0) ? g0 : ((br == 1) ? g1 : g2);
  const float* bptr = (br == 0) ? b0p : ((br == 1) ? b1p : b2p);
  float mu = bnacc_s[br * 64 + o] * (1.0f / POS);
  float var = bnacc_q[br * 64 + o] * (1.0f / POS) - mu * mu;
  float kk = gptr[o] / sqrtf(var + 1e-5f);
  float cc = bptr[o] - mu * kk;
  const float* row = y + (size_t)bb * 262144 + (size_t)h * 4096 + o * 64 + wq * 16;
  float s = 0.0f;
#pragma unroll
  for (int j = 0; j < 4; ++j) {
    float4 v = *(const float4*)(row + j * 4);
    float a;
    a = v.x * kk + cc; s += (a > 0.0f) ? a : 0.0f;
    a = v.y * kk + cc; s += (a > 0.0f) ? a : 0.0f;
    a = v.z * kk + cc; s += (a > 0.0f) ? a : 0.0f;
    a = v.w * kk + cc; s += (a > 0.0f) ? a : 0.0f;
  }
  s += __shfl_down(s, 2, 4);
  s += __shfl_down(s, 1, 4);
  if (wq == 0) atomicAdd(&se_acc[bb * 64 + o], s);
}

// ============ SE MLP fold (blocks 0-5) + global-pool branch (block 6) ============
__global__ void semlp_gp_k(const float* __restrict__ se_acc,
                           const float* __restrict__ bnacc_s, const float* __restrict__ bnacc_q,
                           const float* g0, const float* b0p, const float* g1, const float* b1p,
                           const float* g2, const float* b2p,
                           const float* w10, const float* w11, const float* w12,
                           const float* w20, const float* w21, const float* w22,
                           float* __restrict__ A1, float* __restrict__ A0,
                           const float* __restrict__ xm, const float* __restrict__ gw,
                           const float* __restrict__ gb, const float* __restrict__ bng,
                           const float* __restrict__ bnb, const float* __restrict__ gpw1,
                           const float* __restrict__ gpw2, const float* __restrict__ fuse_w,
                           float* __restrict__ fuse_gp) {
  __shared__ float sm[64];
  __shared__ float g0s[2][64], gp1s[2][64], gpvs[2][64];
  int tid = threadIdx.x;
  if (blockIdx.x < 6) {
    int bb = blockIdx.x, br = bb >> 1;
    const float* w1 = (br == 0) ? w10 : ((br == 1) ? w11 : w12);
    const float* w2 = (br == 0) ? w20 : ((br == 1) ? w21 : w22);
    const float* gptr = (br == 0) ? g0 : ((br == 1) ? g1 : g2);
    const float* bptr = (br == 0) ? b0p : ((br == 1) ? b1p : b2p);
    if (tid < 64) sm[tid] = se_acc[bb * 64 + tid] * (1.0f / HW);
    __syncthreads();
    if (tid < 64) {
      int o = tid;
      float z[4];
#pragma unroll
      for (int j = 0; j < 4; ++j) {
        float s = 0.0f;
        for (int c2 = 0; c2 < 64; ++c2) s += sm[c2] * w1[j * 64 + c2];
        z[j] = (s > 0.0f) ? s : 0.0f;
      }
      float t = 0.0f;
#pragma unroll
      for (int j = 0; j < 4; ++j) t += z[j] * w2[o * 4 + j];
      t = sigmoidf_(t);
      float mu = bnacc_s[br * 64 + o] * (1.0f / POS);
      float var = bnacc_q[br * 64 + o] * (1.0f / POS) - mu * mu;
      float kk = gptr[o] / sqrtf(var + 1e-5f);
      float cc = bptr[o] - mu * kk;
      A1[bb * 64 + o] = kk * t;  // relu(x)*t == relu(x*t), t>0
      A0[bb * 64 + o] = cc * t;
    }
  } else {  // global-pool branch, fully folded into fuse_gp[b][o]
    int b = tid >> 6, o = tid & 63;
    float gv = gb[o];
    for (int i = 0; i < 64; ++i) gv += xm[b * 64 + i] * gw[o * 64 + i];
    g0s[b][o] = gv;
    __syncthreads();
    float mu = 0.5f * (g0s[0][o] + g0s[1][o]);
    float df = g0s[0][o] - g0s[1][o];
    float var = 0.25f * df * df;
    float v = (gv - mu) / sqrtf(var + 1e-5f) * bng[o] + bnb[o];
    v = (v > 0.0f) ? v : 0.0f;
    gp1s[b][o] = v;
    __syncthreads();
    float z[4];
#pragma unroll
    for (int j = 0; j < 4; ++j) {
      float s = 0.0f;
      for (int c2 = 0; c2 < 64; ++c2) s += gp1s[b][c2] * gpw1[j * 64 + c2];
      z[j] = (s > 0.0f) ? s : 0.0f;
    }
    float t = 0.0f;
#pragma unroll
    for (int j = 0; j < 4; ++j) t += z[j] * gpw2[o * 4 + j];
    t = sigmoidf_(t);
    gpvs[b][o] = v * t;
    __syncthreads();
    float fg = 0.0f;
    for (int c2 = 0; c2 < 64; ++c2) fg += fuse_w[o * 256 + 192 + c2] * gpvs[b][c2];
    fuse_gp[b * 64 + o] = fg;
  }
}

// ============ fuse GEMM (w-split, 256 blocks) + atomic BN-stat partials ============
__global__ __launch_bounds__(256) void fuse_k(
    const float* __restrict__ y, const float* __restrict__ A1, const float* __restrict__ A0,
    const float* __restrict__ fwT, const float* __restrict__ fb, const float* __restrict__ fgp,
    float* __restrict__ tmp, float* __restrict__ fstat) {
  int bid = blockIdx.x;                 // [0,256): (b, h, w-half)
  int b = bid >> 7, h = (bid >> 1) & 63, wh = bid & 1;
  int tid = threadIdx.x;
  int wg = tid & 7, og = tid >> 3;      // 8 w-groups x 32 o-groups
  int w0 = wg * 4, o0 = og * 2;
  float acc[2][4] = {};
  __shared__ float As[64][32];
  __shared__ float Ws[64][64];
  for (int br = 0; br < 3; ++br) {
#pragma unroll
    for (int m = 0; m < 8; ++m) {       // stage As: 64 oc x 32 w
      int lin = tid + m * 256;
      int oc = lin >> 5, wl = lin & 31;
      float v = y[(size_t)(br * 2 + b) * 262144 + (size_t)h * 4096 + oc * 64 + wh * 32 + wl];
      float a1 = A1[(br * 2 + b) * 64 + oc], a0 = A0[(br * 2 + b) * 64 + oc];
      v = v * a1 + a0;
      As[oc][wl] = (v > 0.0f) ? v : 0.0f;
    }
#pragma unroll
    for (int m = 0; m < 16; ++m) {      // stage Ws: 64 oc x 64 o
      int lin = tid + m * 256;
      int oc = lin >> 6, ol = lin & 63;
      Ws[oc][ol] = fwT[(br * 64 + oc) * 64 + ol];
    }
    __syncthreads();
#pragma unroll 8
    for (int ict = 0; ict < 64; ++ict) {
      float4 a = *reinterpret_cast<const float4*>(&As[ict][w0]);
      float2 wv = *reinterpret_cast<const float2*>(&Ws[ict][o0]);
      acc[0][0] += wv.x * a.x; acc[0][1] += wv.x * a.y; acc[0][2] += wv.x * a.z; acc[0][3] += wv.x * a.w;
      acc[1][0] += wv.y * a.x; acc[1][1] += wv.y * a.y; acc[1][2] += wv.y * a.z; acc[1][3] += wv.y * a.w;
    }
    __syncthreads();
  }
  float* tp = tmp + (size_t)(b * 64 + h) * 4096 + wh * 32;
  float ps[2], pq[2];
#pragma unroll
  for (int oo = 0; oo < 2; ++oo) {
    int o = o0 + oo;
    float bias = fb[o] + fgp[b * 64 + o];
    float4 v = make_float4(acc[oo][0] + bias, acc[oo][1] + bias,
                           acc[oo][2] + bias, acc[oo][3] + bias);
    *reinterpret_cast<float4*>(&tp[o * 64 + w0]) = v;
    ps[oo] = v.x + v.y + v.z + v.w;
    pq[oo] = v.x * v.x + v.y * v.y + v.z * v.z + v.w * v.w;
  }
  __syncthreads();
#pragma unroll
  for (int oo = 0; oo < 2; ++oo) { As[o0 + oo][wg] = ps[oo]; Ws[o0 + oo][wg] = pq[oo]; }
  __syncthreads();
  if (tid < 64) {
    float s = 0.0f, q = 0.0f;
#pragma unroll
    for (int r = 0; r < 8; ++r) { s += As[tid][r]; q += Ws[tid][r]; }
    atomicAdd(&fstat[tid], s);
    atomicAdd(&fstat[64 + tid], q);
  }
}

// ---------- final BN+relu, write (B,Co,H,W) ----------
__global__ void final_k(const float* __restrict__ tmp, const float* __restrict__ fstat,
                        const float* __restrict__ g, const float* __restrict__ bb,
                        float* __restrict__ out) {
  int lin = blockIdx.x * 256 + threadIdx.x;  // [0, 524288)
  int w = lin & 63, h2 = (lin >> 6) & 63, o = (lin >> 12) & 63, b = lin >> 18;
  float v = tmp[((size_t)(b * 64 + h2) * 64 + o) * 64 + w];
  float m = fstat[o] * (1.0f / POS);
  float var = fstat[64 + o] * (1.0f / POS) - m * m;
  float kk = g[o] / sqrtf(var + 1e-5f);
  float r = (v - m) * kk + bb[o];
  out[lin] = (r > 0.0f) ? r : 0.0f;
}

extern "C" void kernel_launch(void* const* d_in, const int* in_sizes, int n_in,
                              void* d_out, int out_size, void* d_ws, size_t ws_size,
                              hipStream_t stream) {
  const float* x = (const float*)d_in[0];
  const float* base_w[3]   = {(const float*)d_in[1],  (const float*)d_in[7],  (const float*)d_in[13]};
  const float* spline_w[3] = {(const float*)d_in[2],  (const float*)d_in[8],  (const float*)d_in[14]};
  const float* bn_g[3]     = {(const float*)d_in[3],  (const float*)d_in[9],  (const float*)d_in[15]};
  const float* bn_b[3]     = {(const float*)d_in[4],  (const float*)d_in[10], (const float*)d_in[16]};
  const float* se_w1[3]    = {(const float*)d_in[5],  (const float*)d_in[11], (const float*)d_in[17]};
  const float* se_w2[3]    = {(const float*)d_in[6],  (const float*)d_in[12], (const float*)d_in[18]};
  const float* gp_conv_w = (const float*)d_in[19];
  const float* gp_conv_b = (const float*)d_in[20];
  const float* gp_bn_g   = (const float*)d_in[21];
  const float* gp_bn_b   = (const float*)d_in[22];
  const float* gp_se_w1  = (const float*)d_in[23];
  const float* gp_se_w2  = (const float*)d_in[24];
  const float* fuse_w    = (const float*)d_in[25];
  const float* fuse_b    = (const float*)d_in[26];
  const float* fuse_bn_g = (const float*)d_in[27];
  const float* fuse_bn_b = (const float*)d_in[28];
  float* out = (float*)d_out;

  char* wsp = (char*)d_ws;
  auto alloc = [&](size_t bytes) -> char* {
    char* p = wsp;
    wsp += (bytes + 255) & ~(size_t)255;
    return p;
  };
  __hip_bfloat16* F0 = (__hip_bfloat16*)alloc((size_t)2 * 64 * 76 * 448 * 2);
  __hip_bfloat16* F1 = (__hip_bfloat16*)alloc((size_t)2 * 64 * 88 * 640 * 2);
  __hip_bfloat16* F2 = (__hip_bfloat16*)alloc((size_t)2 * 64 * 100 * 832 * 2);
  __hip_bfloat16* W0 = (__hip_bfloat16*)alloc((size_t)9 * 64 * 448 * 2);
  __hip_bfloat16* W1 = (__hip_bfloat16*)alloc((size_t)9 * 64 * 640 * 2);
  __hip_bfloat16* W2 = (__hip_bfloat16*)alloc((size_t)9 * 64 * 832 * 2);
  float* C0r   = (float*)alloc((size_t)3 * 3 * 64 * 4);
  float* ypart = (float*)alloc((size_t)3 * SLAB * 4);   // 3 ki-slabs; slab0 -> y
  float* y     = ypart;
  float* tmp   = ypart + SLAB;   // slab1 dead after rb_k -> reuse
  float* A1  = (float*)alloc(384 * 4);
  float* A0  = (float*)alloc(384 * 4);
  float* xm  = (float*)alloc(128 * 4);
  float* fgp = (float*)alloc(128 * 4);
  float* fwT = (float*)alloc((size_t)12288 * 4);
  float* accz = (float*)alloc(896 * 4);  // fstat[128] | bnacc_s[192] | bnacc_q[192] | se_acc[384]
  float* fstat   = accz;
  float* bnacc_s = accz + 128;
  float* bnacc_q = accz + 320;
  float* se_acc  = accz + 512;

  prepfeat_k<<<12954, 256, 0, stream>>>(x, F0, F1, F2,
                                        base_w[0], spline_w[0], base_w[1], spline_w[1],
                                        base_w[2], spline_w[2], W0, W1, W2, C0r,
                                        fuse_w, fwT, xm, accz);
  conv_all_k<<<576, 128, 0, stream>>>(
      (const short*)F0, (const short*)F1, (const short*)F2,
      (const short*)W0, (const short*)W1, (const short*)W2, C0r, ypart);
  rb_k<<<1536, 256, 0, stream>>>(ypart, bnacc_s, bnacc_q);
  sesum_k<<<384, 256, 0, stream>>>(y, bnacc_s, bnacc_q, bn_g[0], bn_b[0], bn_g[1], bn_b[1],
                                   bn_g[2], bn_b[2], se_acc);
  semlp_gp_k<<<7, 128, 0, stream>>>(se_acc, bnacc_s, bnacc_q, bn_g[0], bn_b[0], bn_g[1], bn_b[1],
                                    bn_g[2], bn_b[2], se_w1[0], se_w1[1], se_w1[2],
                                    se_w2[0], se_w2[1], se_w2[2], A1, A0,
                                    xm, gp_conv_w, gp_conv_b, gp_bn_g, gp_bn_b,
                                    gp_se_w1, gp_se_w2, fuse_w, fgp);
  fuse_k<<<256, 256, 0, stream>>>(y, A1, A0, fwT, fuse_b, fgp, tmp, fstat);
  final_k<<<2048, 256, 0, stream>>>(tmp, fstat, fuse_bn_g, fuse_bn_b, out);
}